// Round 9
// baseline (1776.019 us; speedup 1.0000x reference)
//
#include <hip/hip_runtime.h>
#include <hip/hip_bf16.h>
#include <stdint.h>

#define BB 8
#define CC 512
#define NN 4096
#define QB 64
#define KB 64
#define D4 2048
#define NT (NN / KB)

typedef short bf8 __attribute__((ext_vector_type(8)));
typedef float f32x4 __attribute__((ext_vector_type(4)));

__device__ __forceinline__ uint16_t f2bf(float f) {
  uint32_t u = __builtin_bit_cast(uint32_t, f);
  u = (u + 0x7FFFu + ((u >> 16) & 1u)) >> 16;
  return (uint16_t)u;
}
__device__ __forceinline__ float bf2f(uint16_t u) {
  return __builtin_bit_cast(float, (uint32_t)u << 16);
}

__device__ __forceinline__ void gl_lds16(const void* g, void* l) {
  __builtin_amdgcn_global_load_lds((__attribute__((address_space(1))) void*)g,
                                   (__attribute__((address_space(3))) void*)l, 16, 0, 0);
}

// [B,C,N] fp32 -> [B,N,C] bf16 (optional scale folded in)
__global__ __launch_bounds__(256) void transpose_cast_k(const float* __restrict__ src,
                                                        uint16_t* __restrict__ dst,
                                                        float scale) {
  __shared__ float tile[32][33];
  int b = blockIdx.z;
  int n0 = blockIdx.x * 32, c0 = blockIdx.y * 32;
  int tx = threadIdx.x & 31, ty = threadIdx.x >> 5;
  const float* s = src + ((size_t)b * CC + c0) * NN + n0;
#pragma unroll
  for (int i = 0; i < 4; i++) {
    int c = ty + i * 8;
    tile[tx][c] = s[(size_t)c * NN + tx];
  }
  __syncthreads();
  uint16_t* d = dst + ((size_t)b * NN + n0) * CC + c0;
#pragma unroll
  for (int i = 0; i < 4; i++) {
    int n = ty + i * 8;
    d[(size_t)n * CC + tx] = f2bf(tile[n][tx] * scale);
  }
}

__global__ __launch_bounds__(256) void cast_k(const float* __restrict__ in,
                                              uint16_t* __restrict__ out, int n) {
  int i = (blockIdx.x * 256 + threadIdx.x) * 4;
  if (i >= n) return;
  float4 v = *(const float4*)(in + i);
  ushort4 o;
  o.x = f2bf(v.x); o.y = f2bf(v.y); o.z = f2bf(v.z); o.w = f2bf(v.w);
  *(ushort4*)(out + i) = o;
}

// Flash attention only (R4 loop, slimmed to 73.5 KB LDS + <=128 VGPR so TWO
// blocks co-reside per CU and overlap each other's barrier/latency stalls).
// S kept in bf16; P overwrites S in place (R6-validated). O -> global ws.
__global__ __launch_bounds__(512) __attribute__((amdgpu_waves_per_eu(4))) void attn_k(
    const uint16_t* __restrict__ Qt, const uint16_t* __restrict__ Kt,
    const uint16_t* __restrict__ Vc, uint16_t* __restrict__ Ob) {
  __shared__ __attribute__((aligned(16))) uint16_t Ks[KB][CC];  // 64 KB
  __shared__ __attribute__((aligned(16))) uint16_t SP[QB][72];  // 9 KB: S(bf16)->P in place
  __shared__ float rsc[QB];
  __shared__ float lsf[QB];  // total 75264 B -> 2 blocks/CU

  const int bid = blockIdx.x + gridDim.x * blockIdx.y;
  const int b = bid & 7;          // batch == XCD; co-resident blocks share K/V in L2
  const int n0 = (bid >> 3) * QB;
  const int tid = threadIdx.x;
  const int lane = tid & 63, wid = tid >> 6;
  const int lhi = lane >> 4, llo = lane & 15;
  const int r7 = llo & 7;

  const int srt = wid >> 1;        // S row-tile (q), waves pair up
  const int sct0 = (wid & 1) * 2;  // S col-tiles (k): sct0, sct0+1

  // Q fragments -> registers (once)
  bf8 qf[16];
  {
    const uint16_t* qsrc = Qt + ((size_t)b * NN + n0 + srt * 16 + llo) * CC + lhi * 8;
#pragma unroll
    for (int kc = 0; kc < 16; kc++) qf[kc] = *(const bf8*)(qsrc + kc * 32);
  }

  // K tile 0: DMA global -> LDS (pre-swizzled source, linear dest)
#pragma unroll
  for (int j = 0; j < 8; j++) {
    const int r = wid * 8 + j;
    gl_lds16(Kt + ((size_t)b * NN + r) * CC + ((lane ^ (r & 7)) << 3), &Ks[r][0]);
  }

  const f32x4 vzero = {0.f, 0.f, 0.f, 0.f};
  f32x4 acc[4][4];
#pragma unroll
  for (int i = 0; i < 4; i++)
#pragma unroll
    for (int j = 0; j < 4; j++) acc[i][j] = vzero;

  const uint16_t* k0row = &Ks[sct0 * 16 + llo][0];
  const uint16_t* k1row = &Ks[sct0 * 16 + 16 + llo][0];
  const uint16_t* vbase = Vc + ((size_t)b * CC + wid * 64 + llo) * NN + lhi * 8;
  const int srow = tid >> 3, sj = tid & 7;  // softmax: 8 threads/row
  float m_run = -__builtin_inff(), l_run = 0.f;

  for (int it = 0; it < NT; it++) {
    const int m0 = it * KB;
    // B1: K tile ready (drains DMA)
    asm volatile("s_waitcnt vmcnt(0)" ::: "memory");
    __builtin_amdgcn_s_barrier();

    // S = Q.K^T — Q from regs, K via swizzled conflict-free ds_read_b128
    f32x4 s0 = vzero, s1 = vzero;
    __builtin_amdgcn_s_setprio(1);
#pragma unroll
    for (int kc = 0; kc < 16; kc++) {
      const int g = ((kc * 4 + lhi) ^ r7) << 3;
      bf8 bk0 = *(const bf8*)(k0row + g);
      bf8 bk1 = *(const bf8*)(k1row + g);
      s0 = __builtin_amdgcn_mfma_f32_16x16x32_bf16(qf[kc], bk0, s0, 0, 0, 0);
      s1 = __builtin_amdgcn_mfma_f32_16x16x32_bf16(qf[kc], bk1, s1, 0, 0, 0);
    }
    __builtin_amdgcn_s_setprio(0);
    {
      const int n = srt * 16 + lhi * 4;
#pragma unroll
      for (int r = 0; r < 4; r++) {
        SP[n + r][sct0 * 16 + llo] = f2bf(s0[r]);
        SP[n + r][sct0 * 16 + 16 + llo] = f2bf(s1[r]);
      }
    }
    // B2: S visible, all Ks reads done -> safe to overwrite Ks
    asm volatile("s_waitcnt lgkmcnt(0)" ::: "memory");
    __builtin_amdgcn_s_barrier();

    // V fragments FIRST (oldest -> PV waits vmcnt(8), K-DMA stays in flight)
    bf8 av[2][4];
#pragma unroll
    for (int ks = 0; ks < 2; ks++)
#pragma unroll
      for (int rt = 0; rt < 4; rt++)
        av[ks][rt] = *(const bf8*)(vbase + (size_t)rt * 16 * NN + m0 + ks * 32);
    __builtin_amdgcn_sched_barrier(0);
    // refill K tile (it+1): flies under softmax+PV, drained at next B1
    if (it + 1 < NT) {
#pragma unroll
      for (int j = 0; j < 8; j++) {
        const int r = wid * 8 + j;
        gl_lds16(Kt + ((size_t)b * NN + m0 + KB + r) * CC + ((lane ^ (r & 7)) << 3), &Ks[r][0]);
      }
    }
    __builtin_amdgcn_sched_barrier(0);

    // online softmax (bf16 in, bf16 P out, in-place granule overwrite)
    {
      const bf8 sv8 = *(const bf8*)&SP[srow][sj * 8];
      float sv[8];
#pragma unroll
      for (int k2 = 0; k2 < 8; k2++) sv[k2] = bf2f((uint16_t)sv8[k2]);
      float mx = fmaxf(fmaxf(fmaxf(sv[0], sv[1]), fmaxf(sv[2], sv[3])),
                       fmaxf(fmaxf(sv[4], sv[5]), fmaxf(sv[6], sv[7])));
      mx = fmaxf(mx, __shfl_xor(mx, 1, 8));
      mx = fmaxf(mx, __shfl_xor(mx, 2, 8));
      mx = fmaxf(mx, __shfl_xor(mx, 4, 8));
      const float nm = fmaxf(m_run, mx);
      const float rs = __expf(m_run - nm);
      float p[8], psum = 0.f;
#pragma unroll
      for (int k2 = 0; k2 < 8; k2++) {
        p[k2] = __expf(sv[k2] - nm);
        psum += p[k2];
      }
      bf8 pk;
#pragma unroll
      for (int k2 = 0; k2 < 8; k2++) pk[k2] = (short)f2bf(p[k2]);
      *(bf8*)&SP[srow][sj * 8] = pk;
      psum += __shfl_xor(psum, 1, 8);
      psum += __shfl_xor(psum, 2, 8);
      psum += __shfl_xor(psum, 4, 8);
      l_run = l_run * rs + psum;
      m_run = nm;
      if (sj == 0) {
        rsc[srow] = rs;
        if (it == NT - 1) lsf[srow] = l_run;
      }
    }
    // B3: P + rsc published (LDS only; K-DMA keeps flying)
    asm volatile("s_waitcnt lgkmcnt(0)" ::: "memory");
    __builtin_amdgcn_s_barrier();

    // rescale (cols = n) then PV: acc[c][n] += V[c][m]·P[n][m]
    float rsn[4];
#pragma unroll
    for (int nt = 0; nt < 4; nt++) rsn[nt] = rsc[nt * 16 + llo];
#pragma unroll
    for (int rt = 0; rt < 4; rt++)
#pragma unroll
      for (int nt = 0; nt < 4; nt++) acc[rt][nt] *= rsn[nt];

    __builtin_amdgcn_s_setprio(1);
#pragma unroll
    for (int ks = 0; ks < 2; ks++) {
      bf8 bp[4];
#pragma unroll
      for (int nt = 0; nt < 4; nt++)
        bp[nt] = *(const bf8*)&SP[nt * 16 + llo][(ks * 4 + lhi) * 8];
#pragma unroll
      for (int rt = 0; rt < 4; rt++)
#pragma unroll
        for (int nt = 0; nt < 4; nt++)
          acc[rt][nt] = __builtin_amdgcn_mfma_f32_16x16x32_bf16(av[ks][rt], bp[nt], acc[rt][nt], 0, 0, 0);
    }
    __builtin_amdgcn_s_setprio(0);
  }

  // normalize and write O tile (bf16 [B][N][C]) to ws — L2-resident for the FFN
  float invl[4];
#pragma unroll
  for (int nt = 0; nt < 4; nt++) invl[nt] = 1.0f / lsf[nt * 16 + llo];
#pragma unroll
  for (int rt = 0; rt < 4; rt++)
#pragma unroll
    for (int nt = 0; nt < 4; nt++) {
      ushort4 o4;
      o4.x = f2bf(acc[rt][nt][0] * invl[nt]);
      o4.y = f2bf(acc[rt][nt][1] * invl[nt]);
      o4.z = f2bf(acc[rt][nt][2] * invl[nt]);
      o4.w = f2bf(acc[rt][nt][3] * invl[nt]);
      *(ushort4*)(Ob + ((size_t)b * NN + n0 + nt * 16 + llo) * CC + wid * 64 + rt * 16 + lhi * 4) = o4;
    }
}

// FFN: out = (relu(O.W1^T + b1).W2^T + b2)*gamma + query.  64 tokens/block,
// hidden in 8 slices of 256 staged in 32 KB LDS; O/W1/W2 stream from L2.
__global__ __launch_bounds__(512) __attribute__((amdgpu_waves_per_eu(4))) void ffn_k(
    const uint16_t* __restrict__ Ob, const uint16_t* __restrict__ W1b,
    const uint16_t* __restrict__ W2b, const float* __restrict__ b1,
    const float* __restrict__ b2, const float* __restrict__ gma,
    const float* __restrict__ qry, float* __restrict__ out) {
  __shared__ __attribute__((aligned(16))) uint16_t Hs[QB][256];  // 32 KB

  const int bid = blockIdx.x + gridDim.x * blockIdx.y;
  const int b = bid & 7;
  const int n0 = (bid >> 3) * QB;
  const int tid = threadIdx.x;
  const int lane = tid & 63, wid = tid >> 6;
  const int lhi = lane >> 4, llo = lane & 15;

  const f32x4 vzero = {0.f, 0.f, 0.f, 0.f};
  const uint16_t* ObB = Ob + ((size_t)b * NN + n0) * CC;
  f32x4 facc[4][4];
#pragma unroll
  for (int i = 0; i < 4; i++)
#pragma unroll
    for (int j = 0; j < 4; j++) facc[i][j] = vzero;
  const float g = gma[0];

  for (int sl = 0; sl < 8; sl++) {
    const int dq0 = sl * 256;
    f32x4 hacc[2][4];
#pragma unroll
    for (int i = 0; i < 2; i++)
#pragma unroll
      for (int j = 0; j < 4; j++) hacc[i][j] = vzero;
    __builtin_amdgcn_s_setprio(1);
#pragma unroll 2
    for (int kc = 0; kc < 16; kc++) {
      bf8 bo[4], aw[2];
#pragma unroll
      for (int nt = 0; nt < 4; nt++)
        bo[nt] = *(const bf8*)(ObB + (size_t)(nt * 16 + llo) * CC + kc * 32 + lhi * 8);
#pragma unroll
      for (int dt = 0; dt < 2; dt++)
        aw[dt] = *(const bf8*)(W1b + (size_t)(dq0 + wid * 32 + dt * 16 + llo) * CC + kc * 32 + lhi * 8);
#pragma unroll
      for (int dt = 0; dt < 2; dt++)
#pragma unroll
        for (int nt = 0; nt < 4; nt++)
          hacc[dt][nt] = __builtin_amdgcn_mfma_f32_16x16x32_bf16(aw[dt], bo[nt], hacc[dt][nt], 0, 0, 0);
    }
    __builtin_amdgcn_s_setprio(0);
#pragma unroll
    for (int dt = 0; dt < 2; dt++) {
      const float4 b1v = *(const float4*)(b1 + dq0 + wid * 32 + dt * 16 + lhi * 4);
#pragma unroll
      for (int nt = 0; nt < 4; nt++) {
        ushort4 h4;
        h4.x = f2bf(fmaxf(hacc[dt][nt][0] + b1v.x, 0.f));
        h4.y = f2bf(fmaxf(hacc[dt][nt][1] + b1v.y, 0.f));
        h4.z = f2bf(fmaxf(hacc[dt][nt][2] + b1v.z, 0.f));
        h4.w = f2bf(fmaxf(hacc[dt][nt][3] + b1v.w, 0.f));
        const int row = nt * 16 + llo;
        const int gch = wid * 4 + dt * 2 + (lhi >> 1);
        *(ushort4*)(&Hs[0][0] + row * 256 + ((gch ^ (row & 7)) << 3) + ((lhi & 1) << 2)) = h4;
      }
    }
    __syncthreads();  // H slice visible
    __builtin_amdgcn_s_setprio(1);
#pragma unroll 2
    for (int kd = 0; kd < 8; kd++) {
      bf8 ah[4], bw[4];
#pragma unroll
      for (int nt = 0; nt < 4; nt++) {
        const int row = nt * 16 + llo;
        ah[nt] = *(const bf8*)(&Hs[0][0] + row * 256 + (((kd * 4 + lhi) ^ (row & 7)) << 3));
      }
#pragma unroll
      for (int ct = 0; ct < 4; ct++)
        bw[ct] = *(const bf8*)(W2b + (size_t)(wid * 64 + ct * 16 + llo) * D4 + dq0 + kd * 32 + lhi * 8);
#pragma unroll
      for (int nt = 0; nt < 4; nt++)
#pragma unroll
        for (int ct = 0; ct < 4; ct++)
          facc[nt][ct] = __builtin_amdgcn_mfma_f32_16x16x32_bf16(ah[nt], bw[ct], facc[nt][ct], 0, 0, 0);
    }
    __builtin_amdgcn_s_setprio(0);
    __syncthreads();  // H reads done before next slice overwrites
  }

  // epilogue: out[b,c,n] = (facc + b2[c])*gamma + query (float4 along n)
#pragma unroll
  for (int nt = 0; nt < 4; nt++) {
    const int n = n0 + nt * 16 + lhi * 4;
#pragma unroll
    for (int ct = 0; ct < 4; ct++) {
      const int c = wid * 64 + ct * 16 + llo;
      const float b2c = b2[c];
      const size_t off = ((size_t)b * CC + c) * NN + n;
      const float4 q4 = *(const float4*)(qry + off);
      float4 o4;
      o4.x = (facc[nt][ct][0] + b2c) * g + q4.x;
      o4.y = (facc[nt][ct][1] + b2c) * g + q4.y;
      o4.z = (facc[nt][ct][2] + b2c) * g + q4.z;
      o4.w = (facc[nt][ct][3] + b2c) * g + q4.w;
      *(float4*)(out + off) = o4;
    }
  }
}

extern "C" void kernel_launch(void* const* d_in, const int* in_sizes, int n_in,
                              void* d_out, int out_size, void* d_ws, size_t ws_size,
                              hipStream_t stream) {
  const float* q = (const float*)d_in[0];
  const float* k = (const float*)d_in[1];
  const float* v = (const float*)d_in[2];
  const float* w1 = (const float*)d_in[3];
  const float* b1 = (const float*)d_in[4];
  const float* w2 = (const float*)d_in[5];
  const float* b2 = (const float*)d_in[6];
  const float* gm = (const float*)d_in[7];
  float* out = (float*)d_out;

  uint16_t* Qt = (uint16_t*)d_ws;                    // [B][N][C] bf16 (pre-scaled)  32 MB
  uint16_t* Kt = Qt + (size_t)BB * NN * CC;          // [B][N][C] bf16               32 MB
  uint16_t* Vc = Kt + (size_t)BB * NN * CC;          // [B][C][N] bf16               32 MB
  uint16_t* W1b = Vc + (size_t)BB * NN * CC;         // [2048][512] bf16              2 MB
  uint16_t* W2b = W1b + (size_t)D4 * CC;             // [512][2048] bf16              2 MB
  uint16_t* Ob = W2b + (size_t)CC * D4;              // [B][N][C] bf16 (O)           32 MB

  dim3 tgrid(NN / 32, CC / 32, BB);
  transpose_cast_k<<<tgrid, 256, 0, stream>>>(q, Qt, 0.044194173824159216f);
  transpose_cast_k<<<tgrid, 256, 0, stream>>>(k, Kt, 1.0f);
  cast_k<<<(BB * CC * NN / 4 + 255) / 256, 256, 0, stream>>>(v, Vc, BB * CC * NN);
  cast_k<<<(D4 * CC / 4 + 255) / 256, 256, 0, stream>>>(w1, W1b, D4 * CC);
  cast_k<<<(CC * D4 / 4 + 255) / 256, 256, 0, stream>>>(w2, W2b, CC * D4);
  attn_k<<<dim3(NN / QB, BB), 512, 0, stream>>>(Qt, Kt, Vc, Ob);
  ffn_k<<<dim3(NN / QB, BB), 512, 0, stream>>>(Ob, W1b, W2b, b1, b2, gm, q, out);
}

// Round 10
// 841.195 us; speedup vs baseline: 2.1113x; 2.1113x over previous
//
#include <hip/hip_runtime.h>
#include <hip/hip_bf16.h>
#include <stdint.h>

#define BB 8
#define CC 512
#define NN 4096
#define QB 64
#define KB 64
#define D4 2048
#define NT (NN / KB)

typedef short bf8 __attribute__((ext_vector_type(8)));
typedef float f32x4 __attribute__((ext_vector_type(4)));

__device__ __forceinline__ uint16_t f2bf(float f) {
  uint32_t u = __builtin_bit_cast(uint32_t, f);
  u = (u + 0x7FFFu + ((u >> 16) & 1u)) >> 16;
  return (uint16_t)u;
}
__device__ __forceinline__ float bf2f(uint16_t u) {
  return __builtin_bit_cast(float, (uint32_t)u << 16);
}

__device__ __forceinline__ void gl_lds16(const void* g, void* l) {
  __builtin_amdgcn_global_load_lds((__attribute__((address_space(1))) void*)g,
                                   (__attribute__((address_space(3))) void*)l, 16, 0, 0);
}

// [B,C,N] fp32 -> [B,N,C] bf16 (optional scale folded in)
__global__ __launch_bounds__(256) void transpose_cast_k(const float* __restrict__ src,
                                                        uint16_t* __restrict__ dst,
                                                        float scale) {
  __shared__ float tile[32][33];
  int b = blockIdx.z;
  int n0 = blockIdx.x * 32, c0 = blockIdx.y * 32;
  int tx = threadIdx.x & 31, ty = threadIdx.x >> 5;
  const float* s = src + ((size_t)b * CC + c0) * NN + n0;
#pragma unroll
  for (int i = 0; i < 4; i++) {
    int c = ty + i * 8;
    tile[tx][c] = s[(size_t)c * NN + tx];
  }
  __syncthreads();
  uint16_t* d = dst + ((size_t)b * NN + n0) * CC + c0;
#pragma unroll
  for (int i = 0; i < 4; i++) {
    int n = ty + i * 8;
    d[(size_t)n * CC + tx] = f2bf(tile[n][tx] * scale);
  }
}

__global__ __launch_bounds__(256) void cast_k(const float* __restrict__ in,
                                              uint16_t* __restrict__ out, int n) {
  int i = (blockIdx.x * 256 + threadIdx.x) * 4;
  if (i >= n) return;
  float4 v = *(const float4*)(in + i);
  ushort4 o;
  o.x = f2bf(v.x); o.y = f2bf(v.y); o.z = f2bf(v.z); o.w = f2bf(v.w);
  *(ushort4*)(out + i) = o;
}

// Fused flash-attention + FFN. Fused-phase pipeline:
//   A(t): softmax(t-1)            [VALU]        -> vmcnt(0)+lgkm(0)+barrier
//   B(t): PV(t-1) || QK(t)        [2 indep MFMA+LDS streams] + issue V(t), DMA(t+1)
//         -> lgkm(0)+barrier (DMA/V stay in flight)
// K double-buffered; peeled prologue/epilogue keep the main loop straight-line.
__global__ __launch_bounds__(512) __attribute__((amdgpu_waves_per_eu(2, 2))) void attn_ffn_k(
    const uint16_t* __restrict__ Qt, const uint16_t* __restrict__ Kt,
    const uint16_t* __restrict__ Vc, const uint16_t* __restrict__ W1b,
    const uint16_t* __restrict__ W2b, const float* __restrict__ b1,
    const float* __restrict__ b2, const float* __restrict__ gma,
    const float* __restrict__ qry, float* __restrict__ out) {
  __shared__ __attribute__((aligned(16))) uint16_t Ks[2][KB][CC];  // 128 KB dbuf; FFN overlay
  __shared__ __attribute__((aligned(16))) uint16_t SP[QB][72];     // 9 KB bf16 S
  __shared__ __attribute__((aligned(16))) uint16_t Ps[QB][KB];     // 8 KB swizzled P
  __shared__ float lst[QB];
  __shared__ float rsc[QB];  // total ~146 KB -> 1 block/CU

  const int bid = blockIdx.x + gridDim.x * blockIdx.y;
  const int b = bid & 7;          // batch == XCD round-robin
  const int n0 = (bid >> 3) * QB;
  const int tid = threadIdx.x;
  const int lane = tid & 63, wid = tid >> 6;
  const int lhi = lane >> 4, llo = lane & 15;
  const int r7 = llo & 7;

  const int srt = wid >> 1;        // S row-tile (q), waves pair up
  const int sct0 = (wid & 1) * 2;  // S col-tiles (k): sct0, sct0+1

  // Q fragments -> registers (once)
  bf8 qf[16];
  {
    const uint16_t* qsrc = Qt + ((size_t)b * NN + n0 + srt * 16 + llo) * CC + lhi * 8;
#pragma unroll
    for (int kc = 0; kc < 16; kc++) qf[kc] = *(const bf8*)(qsrc + kc * 32);
  }

  // DMA K(0) -> Ks[0]
#pragma unroll
  for (int j = 0; j < 8; j++) {
    const int r = wid * 8 + j;
    gl_lds16(Kt + ((size_t)b * NN + r) * CC + ((lane ^ (r & 7)) << 3), &Ks[0][r][0]);
  }

  const f32x4 vzero = {0.f, 0.f, 0.f, 0.f};
  f32x4 acc[4][4];
#pragma unroll
  for (int i = 0; i < 4; i++)
#pragma unroll
    for (int j = 0; j < 4; j++) acc[i][j] = vzero;

  const uint16_t* vbase = Vc + ((size_t)b * CC + wid * 64 + llo) * NN + lhi * 8;
  const int srow = tid >> 3, sj = tid & 7;  // softmax mapping: 8 threads/row
  float m_run = -__builtin_inff(), l_run = 0.f;
  bf8 av[2][4];

  // ---------- macro-ish lambdas ----------
  auto QK = [&](int cur, int dummy) {
    const uint16_t* k0row = &Ks[cur][sct0 * 16 + llo][0];
    const uint16_t* k1row = &Ks[cur][sct0 * 16 + 16 + llo][0];
    f32x4 s0 = vzero, s1 = vzero;
#pragma unroll
    for (int kc = 0; kc < 16; kc++) {
      const int g = ((kc * 4 + lhi) ^ r7) << 3;
      bf8 bk0 = *(const bf8*)(k0row + g);
      bf8 bk1 = *(const bf8*)(k1row + g);
      s0 = __builtin_amdgcn_mfma_f32_16x16x32_bf16(qf[kc], bk0, s0, 0, 0, 0);
      s1 = __builtin_amdgcn_mfma_f32_16x16x32_bf16(qf[kc], bk1, s1, 0, 0, 0);
    }
    const int n = srt * 16 + lhi * 4;
#pragma unroll
    for (int r = 0; r < 4; r++) {
      SP[n + r][sct0 * 16 + llo] = f2bf(s0[r]);
      SP[n + r][sct0 * 16 + 16 + llo] = f2bf(s1[r]);
    }
  };

  auto SOFTMAX = [&](bool last) {
    const bf8 sv8 = *(const bf8*)&SP[srow][sj * 8];
    float sv[8];
#pragma unroll
    for (int k2 = 0; k2 < 8; k2++) sv[k2] = bf2f((uint16_t)sv8[k2]);
    float mx = fmaxf(fmaxf(fmaxf(sv[0], sv[1]), fmaxf(sv[2], sv[3])),
                     fmaxf(fmaxf(sv[4], sv[5]), fmaxf(sv[6], sv[7])));
    mx = fmaxf(mx, __shfl_xor(mx, 1, 8));
    mx = fmaxf(mx, __shfl_xor(mx, 2, 8));
    mx = fmaxf(mx, __shfl_xor(mx, 4, 8));
    const float nm = fmaxf(m_run, mx);
    const float rs = __expf(m_run - nm);
    float p[8], psum = 0.f;
#pragma unroll
    for (int k2 = 0; k2 < 8; k2++) {
      p[k2] = __expf(sv[k2] - nm);
      psum += p[k2];
    }
    bf8 pk;
#pragma unroll
    for (int k2 = 0; k2 < 8; k2++) pk[k2] = (short)f2bf(p[k2]);
    *(bf8*)(&Ps[srow][0] + ((sj ^ (srow & 7)) << 3)) = pk;
    psum += __shfl_xor(psum, 1, 8);
    psum += __shfl_xor(psum, 2, 8);
    psum += __shfl_xor(psum, 4, 8);
    l_run = l_run * rs + psum;
    m_run = nm;
    if (sj == 0) {
      rsc[srow] = rs;
      if (last) lst[srow] = l_run;
    }
  };

  auto PV = [&](int dummy) {
    float rsn[4];
#pragma unroll
    for (int nt = 0; nt < 4; nt++) rsn[nt] = rsc[nt * 16 + llo];
#pragma unroll
    for (int rt = 0; rt < 4; rt++)
#pragma unroll
      for (int nt = 0; nt < 4; nt++) acc[rt][nt] *= rsn[nt];
#pragma unroll
    for (int ks = 0; ks < 2; ks++) {
      bf8 bp[4];
#pragma unroll
      for (int nt = 0; nt < 4; nt++)
        bp[nt] = *(const bf8*)(&Ps[nt * 16 + llo][0] + ((((ks << 2) + lhi) ^ r7) << 3));
#pragma unroll
      for (int rt = 0; rt < 4; rt++)
#pragma unroll
        for (int nt = 0; nt < 4; nt++)
          acc[rt][nt] = __builtin_amdgcn_mfma_f32_16x16x32_bf16(av[ks][rt], bp[nt], acc[rt][nt], 0, 0, 0);
    }
  };

  auto VLOAD = [&](int m0) {
#pragma unroll
    for (int ks = 0; ks < 2; ks++)
#pragma unroll
      for (int rt = 0; rt < 4; rt++)
        av[ks][rt] = *(const bf8*)(vbase + (size_t)rt * 16 * NN + m0 + ks * 32);
  };

  auto KDMA = [&](int t, int buf) {
#pragma unroll
    for (int j = 0; j < 8; j++) {
      const int r = wid * 8 + j;
      gl_lds16(Kt + ((size_t)b * NN + t * KB + r) * CC + ((lane ^ (r & 7)) << 3),
               &Ks[buf][r][0]);
    }
  };

  // ---------- peeled pipeline ----------
  // A(0): nothing to softmax; drain DMA(0)
  asm volatile("s_waitcnt vmcnt(0)" ::: "memory");
  __builtin_amdgcn_s_barrier();
  // B(0): QK(0); issue V(0), DMA(1)
  __builtin_amdgcn_s_setprio(1);
  QK(0, 0);
  __builtin_amdgcn_s_setprio(0);
  VLOAD(0);
  KDMA(1, 1);
  asm volatile("s_waitcnt lgkmcnt(0)" ::: "memory");
  __builtin_amdgcn_s_barrier();

  for (int t = 1; t < NT; t++) {
    const int cur = t & 1;
    // A(t): softmax(t-1)
    SOFTMAX(false);
    asm volatile("s_waitcnt vmcnt(0)" ::: "memory");
    __builtin_amdgcn_s_barrier();
    // B(t): PV(t-1) || QK(t) fused, then issue V(t), DMA(t+1)
    __builtin_amdgcn_s_setprio(1);
    PV(0);
    QK(cur, 0);
    __builtin_amdgcn_s_setprio(0);
    VLOAD(t * KB);
    if (t + 1 < NT) KDMA(t + 1, cur ^ 1);
    asm volatile("s_waitcnt lgkmcnt(0)" ::: "memory");
    __builtin_amdgcn_s_barrier();
  }

  // A(NT): softmax(NT-1)
  SOFTMAX(true);
  asm volatile("s_waitcnt vmcnt(0)" ::: "memory");
  __builtin_amdgcn_s_barrier();
  // B(NT): PV(NT-1)
  __builtin_amdgcn_s_setprio(1);
  PV(0);
  __builtin_amdgcn_s_setprio(0);

  __syncthreads();  // all loop LDS traffic done; Ks free for overlays

  float invl[4];
#pragma unroll
  for (int nt = 0; nt < 4; nt++) invl[nt] = 1.0f / lst[nt * 16 + llo];

  // O[n][c] bf16 -> overlay on Ks[0]
  uint16_t(*Old)[CC] = (uint16_t(*)[CC]) & Ks[0][0][0];
#pragma unroll
  for (int rt = 0; rt < 4; rt++)
#pragma unroll
    for (int nt = 0; nt < 4; nt++) {
      ushort4 o4;
      o4.x = f2bf(acc[rt][nt][0] * invl[nt]);
      o4.y = f2bf(acc[rt][nt][1] * invl[nt]);
      o4.z = f2bf(acc[rt][nt][2] * invl[nt]);
      o4.w = f2bf(acc[rt][nt][3] * invl[nt]);
      const int gch = wid * 8 + rt * 2 + (lhi >> 1);
      *(ushort4*)(&Old[nt * 16 + llo][0] + ((gch ^ r7) << 3) + ((lhi & 1) << 2)) = o4;
    }

  // FFN: hidden in 4 d-quarters through Hs (overlay on Ks[1])
  uint16_t(*Hs)[CC] = (uint16_t(*)[CC]) & Ks[1][0][0];
  f32x4 facc[4][4];
#pragma unroll
  for (int i = 0; i < 4; i++)
#pragma unroll
    for (int j = 0; j < 4; j++) facc[i][j] = vzero;
  const float g = gma[0];
  const uint16_t* orow[4];
  const uint16_t* hrow[4];
#pragma unroll
  for (int nt = 0; nt < 4; nt++) {
    orow[nt] = &Old[nt * 16 + llo][0];
    hrow[nt] = &Hs[nt * 16 + llo][0];
  }

  for (int qtr = 0; qtr < 4; qtr++) {
    const int dq0 = qtr * 512;
    f32x4 hacc[4][4];
#pragma unroll
    for (int i = 0; i < 4; i++)
#pragma unroll
      for (int j = 0; j < 4; j++) hacc[i][j] = vzero;
    __syncthreads();  // prev quarter's Hs reads done; O-writes visible (qtr 0)
    __builtin_amdgcn_s_setprio(1);
#pragma unroll 2
    for (int kc8 = 0; kc8 < 64; kc8 += 4) {
      bf8 bo[4], aw[4];
      const int gof = ((kc8 + lhi) ^ r7) << 3;
#pragma unroll
      for (int nt = 0; nt < 4; nt++) bo[nt] = *(const bf8*)(orow[nt] + gof);
#pragma unroll
      for (int dt = 0; dt < 4; dt++) {
        const int d = dq0 + wid * 64 + dt * 16 + llo;
        aw[dt] = *(const bf8*)(W1b + (size_t)d * CC + (kc8 + lhi) * 8);
      }
#pragma unroll
      for (int dt = 0; dt < 4; dt++)
#pragma unroll
        for (int nt = 0; nt < 4; nt++)
          hacc[dt][nt] = __builtin_amdgcn_mfma_f32_16x16x32_bf16(aw[dt], bo[nt], hacc[dt][nt], 0, 0, 0);
    }
    __builtin_amdgcn_s_setprio(0);
#pragma unroll
    for (int dt = 0; dt < 4; dt++) {
      const int dg = dq0 + wid * 64 + dt * 16 + lhi * 4;
      const float4 b1v = *(const float4*)(b1 + dg);
#pragma unroll
      for (int nt = 0; nt < 4; nt++) {
        ushort4 h4;
        h4.x = f2bf(fmaxf(hacc[dt][nt][0] + b1v.x, 0.f));
        h4.y = f2bf(fmaxf(hacc[dt][nt][1] + b1v.y, 0.f));
        h4.z = f2bf(fmaxf(hacc[dt][nt][2] + b1v.z, 0.f));
        h4.w = f2bf(fmaxf(hacc[dt][nt][3] + b1v.w, 0.f));
        const int gch = wid * 8 + dt * 2 + (lhi >> 1);
        *(ushort4*)(&Hs[nt * 16 + llo][0] + ((gch ^ r7) << 3) + ((lhi & 1) << 2)) = h4;
      }
    }
    __syncthreads();  // hidden quarter ready
    __builtin_amdgcn_s_setprio(1);
#pragma unroll 2
    for (int kd8 = 0; kd8 < 64; kd8 += 4) {
      bf8 ah[4], bw[4];
      const int gof = ((kd8 + lhi) ^ r7) << 3;
#pragma unroll
      for (int nt = 0; nt < 4; nt++) ah[nt] = *(const bf8*)(hrow[nt] + gof);
#pragma unroll
      for (int ct = 0; ct < 4; ct++) {
        const int c = wid * 64 + ct * 16 + llo;
        bw[ct] = *(const bf8*)(W2b + (size_t)c * D4 + dq0 + (kd8 + lhi) * 8);
      }
#pragma unroll
      for (int nt = 0; nt < 4; nt++)
#pragma unroll
        for (int ct = 0; ct < 4; ct++)
          facc[nt][ct] = __builtin_amdgcn_mfma_f32_16x16x32_bf16(ah[nt], bw[ct], facc[nt][ct], 0, 0, 0);
    }
    __builtin_amdgcn_s_setprio(0);
  }

  // epilogue: out[b,c,n] = (facc + b2[c])*gamma + query  (float4 along n)
#pragma unroll
  for (int nt = 0; nt < 4; nt++) {
    const int n = n0 + nt * 16 + lhi * 4;
#pragma unroll
    for (int ct = 0; ct < 4; ct++) {
      const int c = wid * 64 + ct * 16 + llo;
      const float b2c = b2[c];
      const size_t off = ((size_t)b * CC + c) * NN + n;
      const float4 q4 = *(const float4*)(qry + off);
      float4 o4;
      o4.x = (facc[nt][ct][0] + b2c) * g + q4.x;
      o4.y = (facc[nt][ct][1] + b2c) * g + q4.y;
      o4.z = (facc[nt][ct][2] + b2c) * g + q4.z;
      o4.w = (facc[nt][ct][3] + b2c) * g + q4.w;
      *(float4*)(out + off) = o4;
    }
  }
}

extern "C" void kernel_launch(void* const* d_in, const int* in_sizes, int n_in,
                              void* d_out, int out_size, void* d_ws, size_t ws_size,
                              hipStream_t stream) {
  const float* q = (const float*)d_in[0];
  const float* k = (const float*)d_in[1];
  const float* v = (const float*)d_in[2];
  const float* w1 = (const float*)d_in[3];
  const float* b1 = (const float*)d_in[4];
  const float* w2 = (const float*)d_in[5];
  const float* b2 = (const float*)d_in[6];
  const float* gm = (const float*)d_in[7];
  float* out = (float*)d_out;

  uint16_t* Qt = (uint16_t*)d_ws;                    // [B][N][C] bf16 (pre-scaled)
  uint16_t* Kt = Qt + (size_t)BB * NN * CC;          // [B][N][C] bf16
  uint16_t* Vc = Kt + (size_t)BB * NN * CC;          // [B][C][N] bf16
  uint16_t* W1b = Vc + (size_t)BB * NN * CC;         // [2048][512] bf16
  uint16_t* W2b = W1b + (size_t)D4 * CC;             // [512][2048] bf16

  dim3 tgrid(NN / 32, CC / 32, BB);
  transpose_cast_k<<<tgrid, 256, 0, stream>>>(q, Qt, 0.044194173824159216f);
  transpose_cast_k<<<tgrid, 256, 0, stream>>>(k, Kt, 1.0f);
  cast_k<<<(BB * CC * NN / 4 + 255) / 256, 256, 0, stream>>>(v, Vc, BB * CC * NN);
  cast_k<<<(D4 * CC / 4 + 255) / 256, 256, 0, stream>>>(w1, W1b, D4 * CC);
  cast_k<<<(CC * D4 / 4 + 255) / 256, 256, 0, stream>>>(w2, W2b, CC * D4);
  attn_ffn_k<<<dim3(NN / QB, BB), 512, 0, stream>>>(Qt, Kt, Vc, W1b, W2b, b1, b2, gm, q, out);
}